// Round 1
// baseline (1423.994 us; speedup 1.0000x reference)
//
#include <hip/hip_runtime.h>

#define HH 181
#define WW 360
#define NPIX (HH*WW)        // 65160
#define NCH 16
#define NHID 256
#define NPIX16 (NCH*NPIX)   // 1042560
#define EPITOL 1e-5f
#define NTERMS 19

// 6th-order upwind RHS at one (channel,h,w) point, geo-cyclic padding done via
// index math (lon: cyclic wrap; lat: pole mirror with +180deg column flip).
__device__ __forceinline__ float rhs_at(const float* __restrict__ qo,
                                        float uu, float vv,
                                        float inv_dlon, float inv_dlat,
                                        int h, int w) {
    const float cp0 = -2.0f/60.0f, cp1 = 15.0f/60.0f, cp2 = -60.0f/60.0f,
                cp3 = 20.0f/60.0f, cp4 = 30.0f/60.0f, cp5 = -3.0f/60.0f;
    const float cn0 =  3.0f/60.0f, cn1 = -30.0f/60.0f, cn2 = -20.0f/60.0f,
                cn3 = 60.0f/60.0f, cn4 = -15.0f/60.0f, cn5 =  2.0f/60.0f;

    // --- longitude taps: row h, cols w-3..w+3 cyclic ---
    const float* row = qo + h * WW;
    float t[7];
#pragma unroll
    for (int i = 0; i < 7; ++i) {
        int wm = w + i - 3;
        wm = (wm < 0) ? wm + WW : wm;
        wm = (wm >= WW) ? wm - WW : wm;
        t[i] = row[wm];
    }
    float dpl = cp0*t[0] + cp1*t[1] + cp2*t[2] + cp3*t[3] + cp4*t[4] + cp5*t[5];
    float dnl = cn0*t[1] + cn1*t[2] + cn2*t[3] + cn3*t[4] + cn4*t[5] + cn5*t[6];

    // --- latitude taps: col w, rows h-3..h+3 with pole mirror ---
    int wf = (w >= WW/2) ? (w - WW/2) : (w + WW/2);
    float s[7];
#pragma unroll
    for (int i = 0; i < 7; ++i) {
        int rr = h + i - 3;
        int wc = w;
        if (rr < 0)            { rr = -1 - rr;        wc = wf; }  // rows -1,-2,-3 -> 0,1,2 (flipped lon)
        else if (rr > HH - 1)  { rr = 2*HH - 1 - rr;  wc = wf; }  // rows 181,182,183 -> 180,179,178
        s[i] = qo[rr * WW + wc];
    }
    float dpa = cp0*s[0] + cp1*s[1] + cp2*s[2] + cp3*s[3] + cp4*s[4] + cp5*s[5];
    float dna = cn0*s[1] + cn1*s[2] + cn2*s[3] + cn3*s[4] + cn4*s[5] + cn5*s[6];

    float dql = (uu > 0.0f ? dpl : dnl) * inv_dlon;
    float dqa = (vv > 0.0f ? dpa : dna) * inv_dlat;
    return -uu * dql - vv * dqa;
}

// K0: transpose W_down (16,256) -> WdT (256,16) so the down-proj weight reads
// are contiguous + wave-uniform (s_load).
__global__ __launch_bounds__(256) void tr_kernel(const float* __restrict__ Wd,
                                                 float* __restrict__ WdT) {
    int i = blockIdx.x * 256 + threadIdx.x;
    if (i < NCH * NHID) {
        int o = i / NHID, c = i - o * NHID;
        WdT[c * NCH + o] = Wd[i];
    }
}

// K1: q[o,pix] = sum_c WdT[c,o] * hidden[c,pix] + b_down[o]
__global__ __launch_bounds__(256) void down_kernel(const float* __restrict__ hid,
                                                   const float* __restrict__ WdT,
                                                   const float* __restrict__ b_down,
                                                   float* __restrict__ q) {
    int pix = blockIdx.x * 256 + threadIdx.x;
    if (pix >= NPIX) return;
    float acc[NCH];
#pragma unroll
    for (int o = 0; o < NCH; ++o) acc[o] = b_down[o];
#pragma unroll 8
    for (int c = 0; c < NHID; ++c) {
        float hv = hid[c * NPIX + pix];
#pragma unroll
        for (int o = 0; o < NCH; ++o) acc[o] += WdT[c * NCH + o] * hv;
    }
#pragma unroll
    for (int o = 0; o < NCH; ++o) q[o * NPIX + pix] = acc[o];
}

// K2: F_n = rhs(q); term0 = result = F_n; zero the per-pass max slots.
__global__ __launch_bounds__(256) void fn_kernel(const float* __restrict__ q,
                                                 const float* __restrict__ u,
                                                 const float* __restrict__ v,
                                                 const float* __restrict__ dlon_p,
                                                 const float* __restrict__ dlat_p,
                                                 float* __restrict__ term0,
                                                 float* __restrict__ result,
                                                 unsigned* __restrict__ maxbuf) {
    if (blockIdx.x == 0 && threadIdx.x < 32) maxbuf[threadIdx.x] = 0u;
    int idx = blockIdx.x * 256 + threadIdx.x;
    if (idx >= NPIX16) return;
    float inv_dlon = 1.0f / dlon_p[0];
    float inv_dlat = 1.0f / dlat_p[0];
    int o = idx / NPIX;
    int pix = idx - o * NPIX;
    int h = pix / WW;
    int w = pix - h * WW;
    float val = rhs_at(q + o * NPIX, u[idx], v[idx], inv_dlon, inv_dlat, h, w);
    term0[idx] = val;
    result[idx] = val;
}

// K3 (x19): new_term = rhs(term_in)*dt/(k+1); result += new_term;
// per-pass global max for the early stop. Pass k skips entirely when
// maxbuf[k-1] < tol (a skipped pass leaves maxbuf[k]=0 -> all later passes skip).
__global__ __launch_bounds__(256) void pass_kernel(const float* __restrict__ tin,
                                                   const float* __restrict__ u,
                                                   const float* __restrict__ v,
                                                   const float* __restrict__ dt_p,
                                                   const float* __restrict__ dlon_p,
                                                   const float* __restrict__ dlat_p,
                                                   float* __restrict__ tout,
                                                   float* __restrict__ result,
                                                   unsigned* __restrict__ maxbuf,
                                                   int k) {
    if (k >= 2) {
        if (__uint_as_float(maxbuf[k - 1]) < EPITOL) return;  // done: term & result frozen
    }
    int idx = blockIdx.x * 256 + threadIdx.x;
    float mval = 0.0f;
    if (idx < NPIX16) {
        float inv_dlon = 1.0f / dlon_p[0];
        float inv_dlat = 1.0f / dlat_p[0];
        float scale = dt_p[0] / ((float)k + 1.0f);
        int o = idx / NPIX;
        int pix = idx - o * NPIX;
        int h = pix / WW;
        int w = pix - h * WW;
        float nt = rhs_at(tin + o * NPIX, u[idx], v[idx], inv_dlon, inv_dlat, h, w) * scale;
        tout[idx] = nt;
        result[idx] += nt;
        mval = fabsf(nt);
    }
    // wave-64 max reduce, one atomic per wave (values >= 0 so uint order == float order)
#pragma unroll
    for (int sft = 32; sft >= 1; sft >>= 1) mval = fmaxf(mval, __shfl_xor(mval, sft));
    if ((threadIdx.x & 63) == 0) atomicMax(maxbuf + k, __float_as_uint(mval));
}

// K4: dwc = (q + result*dt)*dw[o] + db[o]
__global__ __launch_bounds__(256) void dwc_kernel(const float* __restrict__ q,
                                                  const float* __restrict__ result,
                                                  const float* __restrict__ dt_p,
                                                  const float* __restrict__ dw,
                                                  const float* __restrict__ db,
                                                  float* __restrict__ dwc) {
    int idx = blockIdx.x * 256 + threadIdx.x;
    if (idx >= NPIX16) return;
    int o = idx / NPIX;
    float upd = q[idx] + result[idx] * dt_p[0];
    dwc[idx] = upd * dw[o] + db[o];
}

// K5: out[c,pix] = sum_o W_up[c,o]*dwc[o,pix] + b_up[c]; 8 chunks of 32 channels.
__global__ __launch_bounds__(256) void up_kernel(const float* __restrict__ dwc,
                                                 const float* __restrict__ Wu,
                                                 const float* __restrict__ b_up,
                                                 float* __restrict__ out) {
    int pix = blockIdx.x * 256 + threadIdx.x;
    if (pix >= NPIX) return;
    int c0 = blockIdx.y * 32;
    float d[NCH];
#pragma unroll
    for (int o = 0; o < NCH; ++o) d[o] = dwc[o * NPIX + pix];
#pragma unroll 4
    for (int cc = 0; cc < 32; ++cc) {
        int c = c0 + cc;
        float a = b_up[c];
#pragma unroll
        for (int o = 0; o < NCH; ++o) a += Wu[c * NCH + o] * d[o];
        out[c * NPIX + pix] = a;
    }
}

extern "C" void kernel_launch(void* const* d_in, const int* in_sizes, int n_in,
                              void* d_out, int out_size, void* d_ws, size_t ws_size,
                              hipStream_t stream) {
    const float* hidden = (const float*)d_in[0];   // (1,256,181,360)
    const float* u      = (const float*)d_in[1];   // (1,16,181,360)
    const float* v      = (const float*)d_in[2];   // (1,16,181,360)
    const float* dt_p   = (const float*)d_in[3];   // scalar
    const float* dlat_p = (const float*)d_in[4];   // scalar
    const float* dlon_p = (const float*)d_in[5];   // scalar
    const float* W_down = (const float*)d_in[6];   // (16,256)
    const float* b_down = (const float*)d_in[7];   // (16,)
    const float* dw     = (const float*)d_in[8];   // (16,)
    const float* db     = (const float*)d_in[9];   // (16,)
    const float* W_up   = (const float*)d_in[10];  // (256,16)
    const float* b_up   = (const float*)d_in[11];  // (256,)
    float* out = (float*)d_out;

    float* ws = (float*)d_ws;
    float* q      = ws;
    float* t0     = ws + (size_t)NPIX16;
    float* t1     = ws + (size_t)2 * NPIX16;
    float* result = ws + (size_t)3 * NPIX16;
    float* WdT    = ws + (size_t)4 * NPIX16;
    unsigned* maxbuf = (unsigned*)(ws + (size_t)4 * NPIX16 + NCH * NHID);
    float* dwc = t0;  // term buffers are dead after the last pass

    const int nb16 = (NPIX16 + 255) / 256;   // 4073
    const int nbp  = (NPIX + 255) / 256;     // 255

    tr_kernel<<<(NCH * NHID + 255) / 256, 256, 0, stream>>>(W_down, WdT);
    down_kernel<<<nbp, 256, 0, stream>>>(hidden, WdT, b_down, q);
    fn_kernel<<<nb16, 256, 0, stream>>>(q, u, v, dlon_p, dlat_p, t0, result, maxbuf);
    for (int k = 1; k <= NTERMS; ++k) {
        float* tin  = (k & 1) ? t0 : t1;
        float* tout = (k & 1) ? t1 : t0;
        pass_kernel<<<nb16, 256, 0, stream>>>(tin, u, v, dt_p, dlon_p, dlat_p,
                                              tout, result, maxbuf, k);
    }
    dwc_kernel<<<nb16, 256, 0, stream>>>(q, result, dt_p, dw, db, dwc);
    up_kernel<<<dim3(nbp, 8), 256, 0, stream>>>(dwc, W_up, b_up, out);
}

// Round 2
// 165.751 us; speedup vs baseline: 8.5912x; 8.5912x over previous
//
#include <hip/hip_runtime.h>

#define HH 181
#define WW 360
#define NPIX (HH*WW)        // 65160
#define NCH 16
#define NHID 256
#define NPIX16 (NCH*NPIX)   // 1042560
#define EPITOL 1e-5f
#define NTERMS 19

// 6th-order upwind RHS at one (channel,h,w) point, geo-cyclic padding done via
// index math (lon: cyclic wrap; lat: pole mirror with +180deg column flip).
__device__ __forceinline__ float rhs_at(const float* __restrict__ qo,
                                        float uu, float vv,
                                        float inv_dlon, float inv_dlat,
                                        int h, int w) {
    const float cp0 = -2.0f/60.0f, cp1 = 15.0f/60.0f, cp2 = -60.0f/60.0f,
                cp3 = 20.0f/60.0f, cp4 = 30.0f/60.0f, cp5 = -3.0f/60.0f;
    const float cn0 =  3.0f/60.0f, cn1 = -30.0f/60.0f, cn2 = -20.0f/60.0f,
                cn3 = 60.0f/60.0f, cn4 = -15.0f/60.0f, cn5 =  2.0f/60.0f;

    // --- longitude taps: row h, cols w-3..w+3 cyclic ---
    const float* row = qo + h * WW;
    float t[7];
#pragma unroll
    for (int i = 0; i < 7; ++i) {
        int wm = w + i - 3;
        wm = (wm < 0) ? wm + WW : wm;
        wm = (wm >= WW) ? wm - WW : wm;
        t[i] = row[wm];
    }
    float dpl = cp0*t[0] + cp1*t[1] + cp2*t[2] + cp3*t[3] + cp4*t[4] + cp5*t[5];
    float dnl = cn0*t[1] + cn1*t[2] + cn2*t[3] + cn3*t[4] + cn4*t[5] + cn5*t[6];

    // --- latitude taps: col w, rows h-3..h+3 with pole mirror ---
    int wf = (w >= WW/2) ? (w - WW/2) : (w + WW/2);
    float s[7];
#pragma unroll
    for (int i = 0; i < 7; ++i) {
        int rr = h + i - 3;
        int wc = w;
        if (rr < 0)            { rr = -1 - rr;        wc = wf; }  // rows -1,-2,-3 -> 0,1,2 (flipped lon)
        else if (rr > HH - 1)  { rr = 2*HH - 1 - rr;  wc = wf; }  // rows 181,182,183 -> 180,179,178
        s[i] = qo[rr * WW + wc];
    }
    float dpa = cp0*s[0] + cp1*s[1] + cp2*s[2] + cp3*s[3] + cp4*s[4] + cp5*s[5];
    float dna = cn0*s[1] + cn1*s[2] + cn2*s[3] + cn3*s[4] + cn4*s[5] + cn5*s[6];

    float dql = (uu > 0.0f ? dpl : dnl) * inv_dlon;
    float dqa = (vv > 0.0f ? dpa : dna) * inv_dlat;
    return -uu * dql - vv * dqa;
}

// K0: transpose W_down (16,256) -> WdT (256,16) so the down-proj weight reads
// are contiguous + wave-uniform.
__global__ __launch_bounds__(256) void tr_kernel(const float* __restrict__ Wd,
                                                 float* __restrict__ WdT) {
    int i = blockIdx.x * 256 + threadIdx.x;
    if (i < NCH * NHID) {
        int o = i / NHID, c = i - o * NHID;
        WdT[c * NCH + o] = Wd[i];
    }
}

// K1: q[o,pix] = sum_c WdT[c,o] * hidden[c,pix] + b_down[o]
__global__ __launch_bounds__(256) void down_kernel(const float* __restrict__ hid,
                                                   const float* __restrict__ WdT,
                                                   const float* __restrict__ b_down,
                                                   float* __restrict__ q) {
    int pix = blockIdx.x * 256 + threadIdx.x;
    if (pix >= NPIX) return;
    float acc[NCH];
#pragma unroll
    for (int o = 0; o < NCH; ++o) acc[o] = b_down[o];
#pragma unroll 8
    for (int c = 0; c < NHID; ++c) {
        float hv = hid[c * NPIX + pix];
#pragma unroll
        for (int o = 0; o < NCH; ++o) acc[o] += WdT[c * NCH + o] * hv;
    }
#pragma unroll
    for (int o = 0; o < NCH; ++o) q[o * NPIX + pix] = acc[o];
}

// K2: F_n = rhs(q); term0 = result = F_n; zero the per-pass "still big" flags.
__global__ __launch_bounds__(256) void fn_kernel(const float* __restrict__ q,
                                                 const float* __restrict__ u,
                                                 const float* __restrict__ v,
                                                 const float* __restrict__ dlon_p,
                                                 const float* __restrict__ dlat_p,
                                                 float* __restrict__ term0,
                                                 float* __restrict__ result,
                                                 unsigned* __restrict__ flags) {
    if (blockIdx.x == 0 && threadIdx.x < 32) flags[threadIdx.x] = 0u;
    int idx = blockIdx.x * 256 + threadIdx.x;
    if (idx >= NPIX16) return;
    float inv_dlon = 1.0f / dlon_p[0];
    float inv_dlat = 1.0f / dlat_p[0];
    int o = idx / NPIX;
    int pix = idx - o * NPIX;
    int h = pix / WW;
    int w = pix - h * WW;
    float val = rhs_at(q + o * NPIX, u[idx], v[idx], inv_dlon, inv_dlat, h, w);
    term0[idx] = val;
    result[idx] = val;
}

// K3 (x19): new_term = rhs(term_in)*dt/(k+1); result += new_term.
// Early stop: pass k runs iff pass k-1 found max|new_term| >= tol somewhere
// (flags[k-1] != 0). NO atomics: the flag is a boolean, so racy same-value
// plain stores from any block that saw a big value are sufficient. A skipped
// pass leaves flags[k]==0, so all later passes skip too (the `done` latch).
__global__ __launch_bounds__(256) void pass_kernel(const float* __restrict__ tin,
                                                   const float* __restrict__ u,
                                                   const float* __restrict__ v,
                                                   const float* __restrict__ dt_p,
                                                   const float* __restrict__ dlon_p,
                                                   const float* __restrict__ dlat_p,
                                                   float* __restrict__ tout,
                                                   float* __restrict__ result,
                                                   unsigned* __restrict__ flags,
                                                   int k) {
    if (k >= 2) {
        if (flags[k - 1] == 0u) return;  // done: term & result frozen
    }
    int idx = blockIdx.x * 256 + threadIdx.x;
    float mval = 0.0f;
    if (idx < NPIX16) {
        float inv_dlon = 1.0f / dlon_p[0];
        float inv_dlat = 1.0f / dlat_p[0];
        float scale = dt_p[0] / ((float)k + 1.0f);
        int o = idx / NPIX;
        int pix = idx - o * NPIX;
        int h = pix / WW;
        int w = pix - h * WW;
        float nt = rhs_at(tin + o * NPIX, u[idx], v[idx], inv_dlon, inv_dlat, h, w) * scale;
        tout[idx] = nt;
        result[idx] += nt;
        mval = fabsf(nt);
    }
    // block max: wave shfl reduce -> LDS (4 waves) -> thread 0 conditional store
    __shared__ float wmax[4];
#pragma unroll
    for (int sft = 32; sft >= 1; sft >>= 1) mval = fmaxf(mval, __shfl_xor(mval, sft));
    if ((threadIdx.x & 63) == 0) wmax[threadIdx.x >> 6] = mval;
    __syncthreads();
    if (threadIdx.x == 0) {
        float bm = fmaxf(fmaxf(wmax[0], wmax[1]), fmaxf(wmax[2], wmax[3]));
        if (bm >= EPITOL) flags[k] = 1u;   // plain store, no atomic
    }
}

// K4: dwc = (q + result*dt)*dw[o] + db[o]
__global__ __launch_bounds__(256) void dwc_kernel(const float* __restrict__ q,
                                                  const float* __restrict__ result,
                                                  const float* __restrict__ dt_p,
                                                  const float* __restrict__ dw,
                                                  const float* __restrict__ db,
                                                  float* __restrict__ dwc) {
    int idx = blockIdx.x * 256 + threadIdx.x;
    if (idx >= NPIX16) return;
    int o = idx / NPIX;
    float upd = q[idx] + result[idx] * dt_p[0];
    dwc[idx] = upd * dw[o] + db[o];
}

// K5: out[c,pix] = sum_o W_up[c,o]*dwc[o,pix] + b_up[c]; 8 chunks of 32 channels.
__global__ __launch_bounds__(256) void up_kernel(const float* __restrict__ dwc,
                                                 const float* __restrict__ Wu,
                                                 const float* __restrict__ b_up,
                                                 float* __restrict__ out) {
    int pix = blockIdx.x * 256 + threadIdx.x;
    if (pix >= NPIX) return;
    int c0 = blockIdx.y * 32;
    float d[NCH];
#pragma unroll
    for (int o = 0; o < NCH; ++o) d[o] = dwc[o * NPIX + pix];
#pragma unroll 4
    for (int cc = 0; cc < 32; ++cc) {
        int c = c0 + cc;
        float a = b_up[c];
#pragma unroll
        for (int o = 0; o < NCH; ++o) a += Wu[c * NCH + o] * d[o];
        out[c * NPIX + pix] = a;
    }
}

extern "C" void kernel_launch(void* const* d_in, const int* in_sizes, int n_in,
                              void* d_out, int out_size, void* d_ws, size_t ws_size,
                              hipStream_t stream) {
    const float* hidden = (const float*)d_in[0];   // (1,256,181,360)
    const float* u      = (const float*)d_in[1];   // (1,16,181,360)
    const float* v      = (const float*)d_in[2];   // (1,16,181,360)
    const float* dt_p   = (const float*)d_in[3];   // scalar
    const float* dlat_p = (const float*)d_in[4];   // scalar
    const float* dlon_p = (const float*)d_in[5];   // scalar
    const float* W_down = (const float*)d_in[6];   // (16,256)
    const float* b_down = (const float*)d_in[7];   // (16,)
    const float* dw     = (const float*)d_in[8];   // (16,)
    const float* db     = (const float*)d_in[9];   // (16,)
    const float* W_up   = (const float*)d_in[10];  // (256,16)
    const float* b_up   = (const float*)d_in[11];  // (256,)
    float* out = (float*)d_out;

    float* ws = (float*)d_ws;
    float* q      = ws;
    float* t0     = ws + (size_t)NPIX16;
    float* t1     = ws + (size_t)2 * NPIX16;
    float* result = ws + (size_t)3 * NPIX16;
    float* WdT    = ws + (size_t)4 * NPIX16;
    unsigned* flags = (unsigned*)(ws + (size_t)4 * NPIX16 + NCH * NHID);
    float* dwc = t0;  // term buffers are dead after the last pass

    const int nb16 = (NPIX16 + 255) / 256;   // 4073
    const int nbp  = (NPIX + 255) / 256;     // 255

    tr_kernel<<<(NCH * NHID + 255) / 256, 256, 0, stream>>>(W_down, WdT);
    down_kernel<<<nbp, 256, 0, stream>>>(hidden, WdT, b_down, q);
    fn_kernel<<<nb16, 256, 0, stream>>>(q, u, v, dlon_p, dlat_p, t0, result, flags);
    for (int k = 1; k <= NTERMS; ++k) {
        float* tin  = (k & 1) ? t0 : t1;
        float* tout = (k & 1) ? t1 : t0;
        pass_kernel<<<nb16, 256, 0, stream>>>(tin, u, v, dt_p, dlon_p, dlat_p,
                                              tout, result, flags, k);
    }
    dwc_kernel<<<nb16, 256, 0, stream>>>(q, result, dt_p, dw, db, dwc);
    up_kernel<<<dim3(nbp, 8), 256, 0, stream>>>(dwc, W_up, b_up, out);
}